// Round 12
// baseline (27353.052 us; speedup 1.0000x reference)
//
#include <hip/hip_runtime.h>
#include <stdint.h>

#define NN 8192
#define DD 768
#define LOG2E 1.4426950408889634f

typedef unsigned int  U32;
typedef unsigned short U16;
typedef __attribute__((ext_vector_type(8))) short short8;
typedef __attribute__((ext_vector_type(4))) float f32x4;

__device__ __forceinline__ U32 fkey(float x){
  U32 u = __float_as_uint(x);
  return (u & 0x80000000u) ? ~u : (u | 0x80000000u);
}
__device__ __forceinline__ float funkey(U32 k){
  return __uint_as_float((k & 0x80000000u) ? (k ^ 0x80000000u) : ~k);
}
__device__ __forceinline__ float ex2(float x){ return __builtin_amdgcn_exp2f(x); }
__device__ __forceinline__ float rcpf(float x){ return __builtin_amdgcn_rcpf(x); }
__device__ __forceinline__ float bflo(U32 w){ return __uint_as_float(w << 16); }
__device__ __forceinline__ float bfhi(U32 w){ return __uint_as_float(w & 0xFFFF0000u); }
__device__ __forceinline__ U16 tobf(float x){
  U32 a = __float_as_uint(x);
  return (U16)((a + 0x7FFFu + ((a >> 16) & 1u)) >> 16);
}
__device__ __forceinline__ U32 packbf(float lo, float hi){
  U32 a = __float_as_uint(lo), b = __float_as_uint(hi);
  a = a + 0x7FFFu + ((a >> 16) & 1u);
  b = b + 0x7FFFu + ((b >> 16) & 1u);
  return (a >> 16) | (b & 0xFFFF0000u);
}

// slots: 0 qmax 1 qmin 2 maxsqA key 3 maxsqB key
__global__ __launch_bounds__(64) void k_init(U32* slots){
  if (threadIdx.x == 0){ slots[0]=0u; slots[1]=0xFFFFFFFFu; slots[2]=0u; slots[3]=0u; }
}

__global__ __launch_bounds__(256) void k_sqsum(const float* __restrict__ A, const float* __restrict__ B,
                                               float* sqA, float* sqB, U32* slots){
  int wv = threadIdx.x >> 6, ln = threadIdx.x & 63;
  int row = blockIdx.x*4 + wv;
  const float* src = A; float* dst = sqA; U32* slot = slots + 2; int r = row;
  if (row >= NN){ src = B; dst = sqB; slot = slots + 3; r = row - NN; }
  const float* p = src + (size_t)r * DD;
  float s = 0.f;
  #pragma unroll
  for (int m = 0; m < DD/64; ++m){ float v = p[ln + 64*m]; s = fmaf(v, v, s); }
  #pragma unroll
  for (int o = 32; o; o >>= 1) s += __shfl_xor(s, o);
  if (ln == 0){ dst[r] = s; atomicMax(slot, fkey(s)); }
}

// 128x128 tile fp32 Gram -> dist -> u16 quantize; track qmax/qmin
__global__ __launch_bounds__(256) void k_dist(const float* __restrict__ A, const float* __restrict__ B,
                                              U16* __restrict__ q, const float* __restrict__ sqA,
                                              const float* __restrict__ sqB, U32* slots){
  __shared__ float As[16][128], Bs[16][128];
  __shared__ U32 redmx[4], redmn[4];
  const int t = threadIdx.x;
  const int i0 = blockIdx.y*128, j0 = blockIdx.x*128;
  const float S = 65535.f / (sqrtf(funkey(slots[2])) + sqrtf(funkey(slots[3])));
  float acc[8][8];
  #pragma unroll
  for (int m=0;m<8;m++)
    #pragma unroll
    for (int n=0;n<8;n++) acc[m][n] = 0.f;
  const int lr = t >> 1, lk = (t & 1)*8;
  const float* pa = A + (size_t)(i0+lr)*DD + lk;
  const float* pb = B + (size_t)(j0+lr)*DD + lk;
  const int tx = t & 15, ty = t >> 4;
  for (int k0 = 0; k0 < DD; k0 += 16){
    __syncthreads();
    float4 a0 = *(const float4*)(pa + k0);
    float4 a1 = *(const float4*)(pa + k0 + 4);
    float4 b0 = *(const float4*)(pb + k0);
    float4 b1 = *(const float4*)(pb + k0 + 4);
    As[lk+0][lr]=a0.x; As[lk+1][lr]=a0.y; As[lk+2][lr]=a0.z; As[lk+3][lr]=a0.w;
    As[lk+4][lr]=a1.x; As[lk+5][lr]=a1.y; As[lk+6][lr]=a1.z; As[lk+7][lr]=a1.w;
    Bs[lk+0][lr]=b0.x; Bs[lk+1][lr]=b0.y; Bs[lk+2][lr]=b0.z; Bs[lk+3][lr]=b0.w;
    Bs[lk+4][lr]=b1.x; Bs[lk+5][lr]=b1.y; Bs[lk+6][lr]=b1.z; Bs[lk+7][lr]=b1.w;
    __syncthreads();
    #pragma unroll
    for (int kk = 0; kk < 16; ++kk){
      float4 am0 = *(const float4*)&As[kk][ty*8];
      float4 am1 = *(const float4*)&As[kk][ty*8+4];
      float4 bn0 = *(const float4*)&Bs[kk][tx*8];
      float4 bn1 = *(const float4*)&Bs[kk][tx*8+4];
      float ar[8] = {am0.x,am0.y,am0.z,am0.w,am1.x,am1.y,am1.z,am1.w};
      float br[8] = {bn0.x,bn0.y,bn0.z,bn0.w,bn1.x,bn1.y,bn1.z,bn1.w};
      #pragma unroll
      for (int m=0;m<8;m++)
        #pragma unroll
        for (int n=0;n<8;n++) acc[m][n] = fmaf(ar[m], br[n], acc[m][n]);
    }
  }
  U32 bmax = 0u, bmin = 0xFFFFu;
  #pragma unroll
  for (int m=0;m<8;m++){
    int i = i0 + ty*8 + m;
    float sa = sqA[i];
    U16 pk[8] __attribute__((aligned(16)));
    #pragma unroll
    for (int n=0;n<8;n++){
      int j = j0 + tx*8 + n;
      float sq = sa + sqB[j] - 2.f*acc[m][n];
      float d = sqrtf(fmaxf(sq, 0.f));
      d = fmaxf(d, 1e-6f);
      U32 qv = (U32)rintf(d * S);
      if (qv > 65535u) qv = 65535u;
      bmax = bmax > qv ? bmax : qv;
      bmin = bmin < qv ? bmin : qv;
      pk[n] = (U16)qv;
    }
    *(uint4*)(q + (size_t)i*NN + j0 + tx*8) = *(const uint4*)pk;
  }
  #pragma unroll
  for (int o=32;o;o>>=1){
    U32 om = __shfl_xor(bmax, o); bmax = bmax > om ? bmax : om;
    U32 on = __shfl_xor(bmin, o); bmin = bmin < on ? bmin : on;
  }
  if ((t & 63) == 0){ redmx[t>>6] = bmax; redmn[t>>6] = bmin; }
  __syncthreads();
  if (t == 0){
    U32 mx = redmx[0], mn = redmn[0];
    #pragma unroll
    for (int i=1;i<4;i++){ mx = mx > redmx[i] ? mx : redmx[i]; mn = mn < redmn[i] ? mn : redmn[i]; }
    atomicMax(slots+0, mx); atomicMin(slots+1, mn);
  }
}

// in-place u16 q -> bf16 K' = exp(logK + s), s = 50(1+qmin/qmax) ln-units
__global__ __launch_bounds__(256) void k_buildK(U32* K2, const U32* __restrict__ slots){
  const float qmaxf = (float)slots[0];
  const float r0n = (float)slots[1] / qmaxf;
  const float k1 = -100.f*LOG2E/qmaxf;
  const float c2 = 50.f*(1.f + r0n)*LOG2E;
  const float tcl = -1e-4f*LOG2E;
  size_t base = ((size_t)blockIdx.x*256 + threadIdx.x)*4;
  uint4 w = *(uint4*)(K2 + base);
  U32 r[4];
  U32 in[4] = {w.x, w.y, w.z, w.w};
  #pragma unroll
  for (int k=0;k<4;++k){
    float ql = (float)(in[k] & 0xFFFFu);
    float qh = (float)(in[k] >> 16);
    float el = ex2(fminf(ql*k1, tcl) + c2);
    float eh = ex2(fminf(qh*k1, tcl) + c2);
    r[k] = packbf(el, eh);
  }
  *(uint4*)(K2 + base) = make_uint4(r[0], r[1], r[2], r[3]);
}

// ---------------- fused Sinkhorn sweep (R10-proven template, re-parametrized) ----------------
// 1024 blocks x 256 thr (4 waves; 4 blocks/CU via 32KB LDS -> 16 waves/CU).
// Block rc owns rows [8rc, 8rc+8); thread owns 32 cols (4 strips x uint4).
// Per 4-row group: row-dots vs v (LDS, XOR-swizzled) -> wave reduce -> __syncthreads
// -> uu = rcp(rowsum) (written to u[]) -> col partials from the SAME registers.
// FIRST=1: uu = 1/8192, no v read, no barriers.
template<int FIRST>
__global__ __launch_bounds__(256, 4) void k_fused(const uint4* __restrict__ Kp,
                                                  const float* __restrict__ v,
                                                  float* __restrict__ u,
                                                  float* __restrict__ part){
  __shared__ float4 vl4[2048];          // 32 KB
  __shared__ float ws[2][4][4];
  const int t = threadIdx.x;
  const int rc = blockIdx.x;
  const int r0 = rc*8;
  const int wv = t >> 6, ln = t & 63;
  if (!FIRST){
    #pragma unroll
    for (int h = 0; h < 8; ++h){
      int V = t + 256*h;
      vl4[V ^ ((V >> 3) & 7)] = ((const float4*)v)[V];
    }
    __syncthreads();
  }
  float a[4][8];
  #pragma unroll
  for (int s=0;s<4;++s)
    #pragma unroll
    for (int e=0;e<8;++e) a[s][e] = 0.f;

  #pragma unroll
  for (int g=0; g<2; ++g){
    uint4 kw[4][4];                     // [row in group][strip]
    #pragma unroll
    for (int rr=0; rr<4; ++rr)
      #pragma unroll
      for (int s=0; s<4; ++s)
        kw[rr][s] = Kp[(size_t)(r0 + g*4 + rr)*1024 + s*256 + t];
    float uu[4];
    if (!FIRST){
      float d[4] = {0.f,0.f,0.f,0.f};
      #pragma unroll
      for (int s=0; s<4; ++s){
        int V = (s*256 + t)*2;
        int msk = (V >> 3) & 7;         // same for V and V+1 (V even)
        float4 v0 = vl4[V ^ msk];
        float4 v1 = vl4[(V + 1) ^ msk];
        #pragma unroll
        for (int rr=0; rr<4; ++rr){
          uint4 w = kw[rr][s];
          d[rr]=fmaf(bflo(w.x),v0.x,d[rr]); d[rr]=fmaf(bfhi(w.x),v0.y,d[rr]);
          d[rr]=fmaf(bflo(w.y),v0.z,d[rr]); d[rr]=fmaf(bfhi(w.y),v0.w,d[rr]);
          d[rr]=fmaf(bflo(w.z),v1.x,d[rr]); d[rr]=fmaf(bfhi(w.z),v1.y,d[rr]);
          d[rr]=fmaf(bflo(w.w),v1.z,d[rr]); d[rr]=fmaf(bfhi(w.w),v1.w,d[rr]);
        }
      }
      #pragma unroll
      for (int o=32; o; o>>=1){
        #pragma unroll
        for (int rr=0; rr<4; ++rr) d[rr] += __shfl_xor(d[rr], o);
      }
      if (ln == 0){
        #pragma unroll
        for (int rr=0; rr<4; ++rr) ws[g & 1][rr][wv] = d[rr];
      }
      __syncthreads();
      #pragma unroll
      for (int rr=0; rr<4; ++rr)
        uu[rr] = rcpf(ws[g&1][rr][0] + ws[g&1][rr][1] + ws[g&1][rr][2] + ws[g&1][rr][3]);
    } else {
      #pragma unroll
      for (int rr=0; rr<4; ++rr) uu[rr] = 1.0f/8192.0f;
    }
    if (t < 4) u[r0 + g*4 + t] = uu[t];
    #pragma unroll
    for (int rr=0; rr<4; ++rr){
      float ur = uu[rr];
      #pragma unroll
      for (int s=0; s<4; ++s){
        uint4 w = kw[rr][s];
        a[s][0]=fmaf(bflo(w.x),ur,a[s][0]); a[s][1]=fmaf(bfhi(w.x),ur,a[s][1]);
        a[s][2]=fmaf(bflo(w.y),ur,a[s][2]); a[s][3]=fmaf(bfhi(w.y),ur,a[s][3]);
        a[s][4]=fmaf(bflo(w.z),ur,a[s][4]); a[s][5]=fmaf(bfhi(w.z),ur,a[s][5]);
        a[s][6]=fmaf(bflo(w.w),ur,a[s][6]); a[s][7]=fmaf(bfhi(w.w),ur,a[s][7]);
      }
    }
  }
  #pragma unroll
  for (int s=0; s<4; ++s){
    float* pp = part + (size_t)rc*NN + (s*256 + t)*8;
    *(float4*)pp     = make_float4(a[s][0],a[s][1],a[s][2],a[s][3]);
    *(float4*)(pp+4) = make_float4(a[s][4],a[s][5],a[s][6],a[s][7]);
  }
}

// v[c] = 1 / sum over 1024 chunks; 2-stage (8-way split per column + LDS reduce)
__global__ __launch_bounds__(256) void k_vfin(const float* __restrict__ part, float* __restrict__ v){
  __shared__ float red[32][9];
  const int t = threadIdx.x;
  const int ci = t & 31, kk = t >> 5;   // kk in 0..7
  const int c = blockIdx.x*32 + ci;
  float s = 0.f;
  #pragma unroll 8
  for (int m = 0; m < 128; ++m) s += part[(size_t)(kk*128 + m)*NN + c];
  red[ci][kk] = s;
  __syncthreads();
  if (t < 32){
    float q2 = 0.f;
    #pragma unroll
    for (int k=0;k<8;++k) q2 += red[t][k];
    v[blockIdx.x*32 + t] = rcpf(q2);
  }
}

// ---------------- epilogue (verified R6/R8) ----------------
__global__ __launch_bounds__(256) void k_At(const float* __restrict__ A, const float* __restrict__ v,
                                            U16* __restrict__ Ath, U16* __restrict__ Atl){
  __shared__ float Ts[64][65];
  const int t = threadIdx.x;
  const int d0 = blockIdx.x*64, j0 = blockIdx.y*64;
  {
    const int r = t >> 2, cs = (t & 3)*16;
    const float vj = v[j0 + r];
    #pragma unroll
    for (int e=0;e<4;++e){
      float4 a4 = *(const float4*)(A + (size_t)(j0+r)*DD + d0 + cs + e*4);
      Ts[r][cs+e*4+0]=a4.x*vj; Ts[r][cs+e*4+1]=a4.y*vj;
      Ts[r][cs+e*4+2]=a4.z*vj; Ts[r][cs+e*4+3]=a4.w*vj;
    }
  }
  __syncthreads();
  {
    const int dr = t >> 2, jseg = t & 3;
    U16 hh[16], ll[16];
    #pragma unroll
    for (int e=0;e<16;++e){
      float x = Ts[jseg*16+e][dr];
      U16 h = tobf(x);
      hh[e] = h;
      ll[e] = tobf(x - __uint_as_float(((U32)h) << 16));
    }
    size_t off = (size_t)(d0+dr)*NN + j0 + jseg*16;
    *(uint4*)(Ath + off)     = *(const uint4*)&hh[0];
    *(uint4*)(Ath + off + 8) = *(const uint4*)&hh[8];
    *(uint4*)(Atl + off)     = *(const uint4*)&ll[0];
    *(uint4*)(Atl + off + 8) = *(const uint4*)&ll[8];
  }
}

__global__ __launch_bounds__(512) void k_outA(const U16* __restrict__ Kp,
                                              const U16* __restrict__ Ath, const U16* __restrict__ Atl,
                                              const float* __restrict__ u, float* __restrict__ outA){
  __shared__ U16 Ks[128][40];
  __shared__ U16 Ah[192][40];
  __shared__ U16 Al[192][40];
  const int t = threadIdx.x;
  const int i0 = blockIdx.y*128, d0 = blockIdx.x*192;
  const int w  = t >> 6, lane = t & 63;
  const int wm = w >> 1, wn = w & 1;
  const int l15 = lane & 15, lhi = lane >> 4;
  f32x4 acc[2][6];
  #pragma unroll
  for (int fm=0;fm<2;++fm)
    #pragma unroll
    for (int fn=0;fn<6;++fn) acc[fm][fn] = (f32x4){0.f,0.f,0.f,0.f};

  const int sr = t >> 2, sseg = t & 3;
  for (int j0 = 0; j0 < NN; j0 += 32){
    __syncthreads();
    {
      uint4 kw = *(const uint4*)(Kp + (size_t)(i0+sr)*NN + j0 + sseg*8);
      *(uint4*)&Ks[sr][sseg*8] = kw;
      #pragma unroll
      for (int uu=0; uu<3; ++uu){
        int id = t + 512*uu;
        if (id < 768){
          int r = id >> 2, seg = id & 3;
          uint4 aw = *(const uint4*)(Ath + (size_t)(d0+r)*NN + j0 + seg*8);
          *(uint4*)&Ah[r][seg*8] = aw;
        } else {
          int rid = id - 768;
          int r = rid >> 2, seg = rid & 3;
          uint4 aw = *(const uint4*)(Atl + (size_t)(d0+r)*NN + j0 + seg*8);
          *(uint4*)&Al[r][seg*8] = aw;
        }
      }
    }
    __syncthreads();
    short8 af[2];
    #pragma unroll
    for (int fm=0;fm<2;++fm)
      af[fm] = *(const short8*)&Ks[wm*32 + fm*16 + l15][lhi*8];
    #pragma unroll
    for (int fn=0;fn<6;++fn){
      short8 bh = *(const short8*)&Ah[wn*96 + fn*16 + l15][lhi*8];
      short8 bl = *(const short8*)&Al[wn*96 + fn*16 + l15][lhi*8];
      #pragma unroll
      for (int fm=0;fm<2;++fm){
        acc[fm][fn] = __builtin_amdgcn_mfma_f32_16x16x32_bf16(af[fm], bh, acc[fm][fn], 0, 0, 0);
        acc[fm][fn] = __builtin_amdgcn_mfma_f32_16x16x32_bf16(af[fm], bl, acc[fm][fn], 0, 0, 0);
      }
    }
  }
  float us[2][4];
  #pragma unroll
  for (int fm=0;fm<2;++fm)
    #pragma unroll
    for (int r=0;r<4;++r) us[fm][r] = u[i0 + wm*32 + fm*16 + lhi*4 + r];
  #pragma unroll
  for (int fm=0;fm<2;++fm)
    #pragma unroll
    for (int fn=0;fn<6;++fn)
      #pragma unroll
      for (int r=0;r<4;++r){
        int i = i0 + wm*32 + fm*16 + lhi*4 + r;
        int d = d0 + wn*96 + fn*16 + l15;
        outA[(size_t)i*DD + d] = acc[fm][fn][r] * us[fm][r];
      }
}

__global__ __launch_bounds__(256) void k_outB(const U16* __restrict__ Kp, const float* __restrict__ B,
                                              const float* __restrict__ u, const float* __restrict__ v,
                                              float* __restrict__ outB){
  __shared__ float Tt[64][65];
  const int t = threadIdx.x;
  const int j0t = blockIdx.y*64, d0 = blockIdx.x*128;
  const int jc = t & 63, ig = t >> 6;
  const int dg = t & 31, jg = t >> 5;
  float4 acc[8];
  #pragma unroll
  for (int m=0;m<8;m++) acc[m] = make_float4(0.f,0.f,0.f,0.f);
  for (int i0 = 0; i0 < NN; i0 += 64){
    __syncthreads();
    #pragma unroll
    for (int m=0;m<16;m++){
      int i = i0 + ig*16 + m;
      U32 kb = ((U32)Kp[(size_t)i*NN + j0t + jc]) << 16;
      Tt[jc][ig*16+m] = __uint_as_float(kb) * u[i];
    }
    __syncthreads();
    #pragma unroll 4
    for (int ii = 0; ii < 64; ++ii){
      float4 b4 = *(const float4*)(B + (size_t)(i0+ii)*DD + d0 + dg*4);
      #pragma unroll
      for (int m=0;m<8;m++){
        float tv = Tt[jg*8+m][ii];
        acc[m].x = fmaf(tv, b4.x, acc[m].x);
        acc[m].y = fmaf(tv, b4.y, acc[m].y);
        acc[m].z = fmaf(tv, b4.z, acc[m].z);
        acc[m].w = fmaf(tv, b4.w, acc[m].w);
      }
    }
  }
  #pragma unroll
  for (int m=0;m<8;m++){
    int j = j0t + jg*8 + m;
    float vj = v[j];
    acc[m].x *= vj; acc[m].y *= vj; acc[m].z *= vj; acc[m].w *= vj;
    *(float4*)(outB + (size_t)j*DD + d0 + dg*4) = acc[m];
  }
}

extern "C" void kernel_launch(void* const* d_in, const int* in_sizes, int n_in,
                              void* d_out, int out_size, void* d_ws, size_t ws_size,
                              hipStream_t stream) {
  const float* A = (const float*)d_in[0];
  const float* B = (const float*)d_in[1];
  float* out = (float*)d_out;
  char* ws = (char*)d_ws;
  U16*  q     = (U16*) (ws);                          // 134217728 B
  float* u    = (float*)(ws + 136314880);
  float* v    = (float*)(ws + 136347648);
  float* sqA  = (float*)(ws + 136380416);
  float* sqB  = (float*)(ws + 136413184);
  U32*  slots = (U32*) (ws + 136445952);
  float* part = (float*)(ws + 136511552);             // 1024*8192*4 = 33.5 MB (region proven in R7)
  // At scratch lives in d_out's second half (dead until k_outB writes it):
  U16* Ath = (U16*)(out + (size_t)NN*DD);
  U16* Atl = Ath + (size_t)NN*DD;

  k_init<<<1, 64, 0, stream>>>(slots);
  k_sqsum<<<4096, 256, 0, stream>>>(A, B, sqA, sqB, slots);
  k_dist<<<dim3(64,64), 256, 0, stream>>>(A, B, q, sqA, sqB, slots);
  k_buildK<<<32768, 256, 0, stream>>>((U32*)q, slots);

  const uint4* Kp4 = (const uint4*)q;
  k_fused<1><<<1024, 256, 0, stream>>>(Kp4, v, u, part);
  for (int it = 0; it < 200; ++it){
    k_vfin<<<256, 256, 0, stream>>>(part, v);
    k_fused<0><<<1024, 256, 0, stream>>>(Kp4, v, u, part);
  }

  k_At<<<dim3(12,128), 256, 0, stream>>>(A, v, Ath, Atl);
  k_outA<<<dim3(4,64), 512, 0, stream>>>(q, Ath, Atl, u, out);
  k_outB<<<dim3(6,128), 256, 0, stream>>>(q, B, u, v, out + (size_t)NN*DD);
}

// Round 13
// 12446.184 us; speedup vs baseline: 2.1977x; 2.1977x over previous
//
#include <hip/hip_runtime.h>
#include <stdint.h>

#define NN 8192
#define DD 768
#define LOG2E 1.4426950408889634f

typedef unsigned int  U32;
typedef unsigned short U16;
typedef __attribute__((ext_vector_type(8))) short short8;
typedef __attribute__((ext_vector_type(4))) float f32x4;

__device__ __forceinline__ U32 fkey(float x){
  U32 u = __float_as_uint(x);
  return (u & 0x80000000u) ? ~u : (u | 0x80000000u);
}
__device__ __forceinline__ float funkey(U32 k){
  return __uint_as_float((k & 0x80000000u) ? (k ^ 0x80000000u) : ~k);
}
__device__ __forceinline__ float ex2(float x){ return __builtin_amdgcn_exp2f(x); }
__device__ __forceinline__ float rcpf(float x){ return __builtin_amdgcn_rcpf(x); }
__device__ __forceinline__ float bflo(U32 w){ return __uint_as_float(w << 16); }
__device__ __forceinline__ float bfhi(U32 w){ return __uint_as_float(w & 0xFFFF0000u); }
__device__ __forceinline__ U16 tobf(float x){
  U32 a = __float_as_uint(x);
  return (U16)((a + 0x7FFFu + ((a >> 16) & 1u)) >> 16);
}
__device__ __forceinline__ U32 packbf(float lo, float hi){
  U32 a = __float_as_uint(lo), b = __float_as_uint(hi);
  a = a + 0x7FFFu + ((a >> 16) & 1u);
  b = b + 0x7FFFu + ((b >> 16) & 1u);
  return (a >> 16) | (b & 0xFFFF0000u);
}

// slots: 0 qmax 1 qmin 2 maxsqA key 3 maxsqB key
__global__ __launch_bounds__(64) void k_init(U32* slots){
  if (threadIdx.x == 0){ slots[0]=0u; slots[1]=0xFFFFFFFFu; slots[2]=0u; slots[3]=0u; }
}

__global__ __launch_bounds__(256) void k_sqsum(const float* __restrict__ A, const float* __restrict__ B,
                                               float* sqA, float* sqB, U32* slots){
  int wv = threadIdx.x >> 6, ln = threadIdx.x & 63;
  int row = blockIdx.x*4 + wv;
  const float* src = A; float* dst = sqA; U32* slot = slots + 2; int r = row;
  if (row >= NN){ src = B; dst = sqB; slot = slots + 3; r = row - NN; }
  const float* p = src + (size_t)r * DD;
  float s = 0.f;
  #pragma unroll
  for (int m = 0; m < DD/64; ++m){ float v = p[ln + 64*m]; s = fmaf(v, v, s); }
  #pragma unroll
  for (int o = 32; o; o >>= 1) s += __shfl_xor(s, o);
  if (ln == 0){ dst[r] = s; atomicMax(slot, fkey(s)); }
}

// 128x128 tile fp32 Gram -> dist -> u16 quantize; track qmax/qmin
__global__ __launch_bounds__(256) void k_dist(const float* __restrict__ A, const float* __restrict__ B,
                                              U16* __restrict__ q, const float* __restrict__ sqA,
                                              const float* __restrict__ sqB, U32* slots){
  __shared__ float As[16][128], Bs[16][128];
  __shared__ U32 redmx[4], redmn[4];
  const int t = threadIdx.x;
  const int i0 = blockIdx.y*128, j0 = blockIdx.x*128;
  const float S = 65535.f / (sqrtf(funkey(slots[2])) + sqrtf(funkey(slots[3])));
  float acc[8][8];
  #pragma unroll
  for (int m=0;m<8;m++)
    #pragma unroll
    for (int n=0;n<8;n++) acc[m][n] = 0.f;
  const int lr = t >> 1, lk = (t & 1)*8;
  const float* pa = A + (size_t)(i0+lr)*DD + lk;
  const float* pb = B + (size_t)(j0+lr)*DD + lk;
  const int tx = t & 15, ty = t >> 4;
  for (int k0 = 0; k0 < DD; k0 += 16){
    __syncthreads();
    float4 a0 = *(const float4*)(pa + k0);
    float4 a1 = *(const float4*)(pa + k0 + 4);
    float4 b0 = *(const float4*)(pb + k0);
    float4 b1 = *(const float4*)(pb + k0 + 4);
    As[lk+0][lr]=a0.x; As[lk+1][lr]=a0.y; As[lk+2][lr]=a0.z; As[lk+3][lr]=a0.w;
    As[lk+4][lr]=a1.x; As[lk+5][lr]=a1.y; As[lk+6][lr]=a1.z; As[lk+7][lr]=a1.w;
    Bs[lk+0][lr]=b0.x; Bs[lk+1][lr]=b0.y; Bs[lk+2][lr]=b0.z; Bs[lk+3][lr]=b0.w;
    Bs[lk+4][lr]=b1.x; Bs[lk+5][lr]=b1.y; Bs[lk+6][lr]=b1.z; Bs[lk+7][lr]=b1.w;
    __syncthreads();
    #pragma unroll
    for (int kk = 0; kk < 16; ++kk){
      float4 am0 = *(const float4*)&As[kk][ty*8];
      float4 am1 = *(const float4*)&As[kk][ty*8+4];
      float4 bn0 = *(const float4*)&Bs[kk][tx*8];
      float4 bn1 = *(const float4*)&Bs[kk][tx*8+4];
      float ar[8] = {am0.x,am0.y,am0.z,am0.w,am1.x,am1.y,am1.z,am1.w};
      float br[8] = {bn0.x,bn0.y,bn0.z,bn0.w,bn1.x,bn1.y,bn1.z,bn1.w};
      #pragma unroll
      for (int m=0;m<8;m++)
        #pragma unroll
        for (int n=0;n<8;n++) acc[m][n] = fmaf(ar[m], br[n], acc[m][n]);
    }
  }
  U32 bmax = 0u, bmin = 0xFFFFu;
  #pragma unroll
  for (int m=0;m<8;m++){
    int i = i0 + ty*8 + m;
    float sa = sqA[i];
    U16 pk[8] __attribute__((aligned(16)));
    #pragma unroll
    for (int n=0;n<8;n++){
      int j = j0 + tx*8 + n;
      float sq = sa + sqB[j] - 2.f*acc[m][n];
      float d = sqrtf(fmaxf(sq, 0.f));
      d = fmaxf(d, 1e-6f);
      U32 qv = (U32)rintf(d * S);
      if (qv > 65535u) qv = 65535u;
      bmax = bmax > qv ? bmax : qv;
      bmin = bmin < qv ? bmin : qv;
      pk[n] = (U16)qv;
    }
    *(uint4*)(q + (size_t)i*NN + j0 + tx*8) = *(const uint4*)pk;
  }
  #pragma unroll
  for (int o=32;o;o>>=1){
    U32 om = __shfl_xor(bmax, o); bmax = bmax > om ? bmax : om;
    U32 on = __shfl_xor(bmin, o); bmin = bmin < on ? bmin : on;
  }
  if ((t & 63) == 0){ redmx[t>>6] = bmax; redmn[t>>6] = bmin; }
  __syncthreads();
  if (t == 0){
    U32 mx = redmx[0], mn = redmn[0];
    #pragma unroll
    for (int i=1;i<4;i++){ mx = mx > redmx[i] ? mx : redmx[i]; mn = mn < redmn[i] ? mn : redmn[i]; }
    atomicMax(slots+0, mx); atomicMin(slots+1, mn);
  }
}

// in-place u16 q -> bf16 K' = exp(logK + s), s = 50(1+qmin/qmax) ln-units
__global__ __launch_bounds__(256) void k_buildK(U32* K2, const U32* __restrict__ slots){
  const float qmaxf = (float)slots[0];
  const float r0n = (float)slots[1] / qmaxf;
  const float k1 = -100.f*LOG2E/qmaxf;
  const float c2 = 50.f*(1.f + r0n)*LOG2E;
  const float tcl = -1e-4f*LOG2E;
  size_t base = ((size_t)blockIdx.x*256 + threadIdx.x)*4;
  uint4 w = *(uint4*)(K2 + base);
  U32 r[4];
  U32 in[4] = {w.x, w.y, w.z, w.w};
  #pragma unroll
  for (int k=0;k<4;++k){
    float ql = (float)(in[k] & 0xFFFFu);
    float qh = (float)(in[k] >> 16);
    float el = ex2(fminf(ql*k1, tcl) + c2);
    float eh = ex2(fminf(qh*k1, tcl) + c2);
    r[k] = packbf(el, eh);
  }
  *(uint4*)(K2 + base) = make_uint4(r[0], r[1], r[2], r[3]);
}

// ---------------- fused Sinkhorn sweep (R10-proven template; no VGPR cap) ----------------
// 1024 blocks x 256 thr. Block rc owns rows [8rc, 8rc+8); thread owns 32 cols.
// Per 4-row group: row-dots vs v (LDS, XOR-swizzled) -> wave reduce -> __syncthreads
// -> uu = rcp(rowsum) (written to u[]) -> col partials from the SAME registers.
// FIRST=1: uu = 1/8192, no v read, no barriers.
template<int FIRST>
__global__ __launch_bounds__(256) void k_fused(const uint4* __restrict__ Kp,
                                               const float* __restrict__ v,
                                               float* __restrict__ u,
                                               float* __restrict__ part){
  __shared__ float4 vl4[2048];          // 32 KB
  __shared__ float ws[2][4][4];
  const int t = threadIdx.x;
  const int rc = blockIdx.x;
  const int r0 = rc*8;
  const int wv = t >> 6, ln = t & 63;
  if (!FIRST){
    #pragma unroll
    for (int h = 0; h < 8; ++h){
      int V = t + 256*h;
      vl4[V ^ ((V >> 3) & 7)] = ((const float4*)v)[V];
    }
    __syncthreads();
  }
  float a[4][8];
  #pragma unroll
  for (int s=0;s<4;++s)
    #pragma unroll
    for (int e=0;e<8;++e) a[s][e] = 0.f;

  #pragma unroll
  for (int g=0; g<2; ++g){
    uint4 kw[4][4];                     // [row in group][strip]
    #pragma unroll
    for (int rr=0; rr<4; ++rr)
      #pragma unroll
      for (int s=0; s<4; ++s)
        kw[rr][s] = Kp[(size_t)(r0 + g*4 + rr)*1024 + s*256 + t];
    float uu[4];
    if (!FIRST){
      float d[4] = {0.f,0.f,0.f,0.f};
      #pragma unroll
      for (int s=0; s<4; ++s){
        int V = (s*256 + t)*2;
        int msk = (V >> 3) & 7;         // same for V and V+1 (V even)
        float4 v0 = vl4[V ^ msk];
        float4 v1 = vl4[(V + 1) ^ msk];
        #pragma unroll
        for (int rr=0; rr<4; ++rr){
          uint4 w = kw[rr][s];
          d[rr]=fmaf(bflo(w.x),v0.x,d[rr]); d[rr]=fmaf(bfhi(w.x),v0.y,d[rr]);
          d[rr]=fmaf(bflo(w.y),v0.z,d[rr]); d[rr]=fmaf(bfhi(w.y),v0.w,d[rr]);
          d[rr]=fmaf(bflo(w.z),v1.x,d[rr]); d[rr]=fmaf(bfhi(w.z),v1.y,d[rr]);
          d[rr]=fmaf(bflo(w.w),v1.z,d[rr]); d[rr]=fmaf(bfhi(w.w),v1.w,d[rr]);
        }
      }
      #pragma unroll
      for (int o=32; o; o>>=1){
        #pragma unroll
        for (int rr=0; rr<4; ++rr) d[rr] += __shfl_xor(d[rr], o);
      }
      if (ln == 0){
        #pragma unroll
        for (int rr=0; rr<4; ++rr) ws[g & 1][rr][wv] = d[rr];
      }
      __syncthreads();
      #pragma unroll
      for (int rr=0; rr<4; ++rr)
        uu[rr] = rcpf(ws[g&1][rr][0] + ws[g&1][rr][1] + ws[g&1][rr][2] + ws[g&1][rr][3]);
    } else {
      #pragma unroll
      for (int rr=0; rr<4; ++rr) uu[rr] = 1.0f/8192.0f;
    }
    if (t < 4) u[r0 + g*4 + t] = uu[t];
    #pragma unroll
    for (int rr=0; rr<4; ++rr){
      float ur = uu[rr];
      #pragma unroll
      for (int s=0; s<4; ++s){
        uint4 w = kw[rr][s];
        a[s][0]=fmaf(bflo(w.x),ur,a[s][0]); a[s][1]=fmaf(bfhi(w.x),ur,a[s][1]);
        a[s][2]=fmaf(bflo(w.y),ur,a[s][2]); a[s][3]=fmaf(bfhi(w.y),ur,a[s][3]);
        a[s][4]=fmaf(bflo(w.z),ur,a[s][4]); a[s][5]=fmaf(bfhi(w.z),ur,a[s][5]);
        a[s][6]=fmaf(bflo(w.w),ur,a[s][6]); a[s][7]=fmaf(bfhi(w.w),ur,a[s][7]);
      }
    }
  }
  #pragma unroll
  for (int s=0; s<4; ++s){
    float* pp = part + (size_t)rc*NN + (s*256 + t)*8;
    *(float4*)pp     = make_float4(a[s][0],a[s][1],a[s][2],a[s][3]);
    *(float4*)(pp+4) = make_float4(a[s][4],a[s][5],a[s][6],a[s][7]);
  }
}

// v[c] = 1 / sum over 1024 chunks; 2-stage (8-way split per column + LDS reduce)
__global__ __launch_bounds__(256) void k_vfin(const float* __restrict__ part, float* __restrict__ v){
  __shared__ float red[32][9];
  const int t = threadIdx.x;
  const int ci = t & 31, kk = t >> 5;   // kk in 0..7
  const int c = blockIdx.x*32 + ci;
  float s = 0.f;
  #pragma unroll 8
  for (int m = 0; m < 128; ++m) s += part[(size_t)(kk*128 + m)*NN + c];
  red[ci][kk] = s;
  __syncthreads();
  if (t < 32){
    float q2 = 0.f;
    #pragma unroll
    for (int k=0;k<8;++k) q2 += red[t][k];
    v[blockIdx.x*32 + t] = rcpf(q2);
  }
}

// ---------------- epilogue (verified R6/R8) ----------------
__global__ __launch_bounds__(256) void k_At(const float* __restrict__ A, const float* __restrict__ v,
                                            U16* __restrict__ Ath, U16* __restrict__ Atl){
  __shared__ float Ts[64][65];
  const int t = threadIdx.x;
  const int d0 = blockIdx.x*64, j0 = blockIdx.y*64;
  {
    const int r = t >> 2, cs = (t & 3)*16;
    const float vj = v[j0 + r];
    #pragma unroll
    for (int e=0;e<4;++e){
      float4 a4 = *(const float4*)(A + (size_t)(j0+r)*DD + d0 + cs + e*4);
      Ts[r][cs+e*4+0]=a4.x*vj; Ts[r][cs+e*4+1]=a4.y*vj;
      Ts[r][cs+e*4+2]=a4.z*vj; Ts[r][cs+e*4+3]=a4.w*vj;
    }
  }
  __syncthreads();
  {
    const int dr = t >> 2, jseg = t & 3;
    U16 hh[16], ll[16];
    #pragma unroll
    for (int e=0;e<16;++e){
      float x = Ts[jseg*16+e][dr];
      U16 h = tobf(x);
      hh[e] = h;
      ll[e] = tobf(x - __uint_as_float(((U32)h) << 16));
    }
    size_t off = (size_t)(d0+dr)*NN + j0 + jseg*16;
    *(uint4*)(Ath + off)     = *(const uint4*)&hh[0];
    *(uint4*)(Ath + off + 8) = *(const uint4*)&hh[8];
    *(uint4*)(Atl + off)     = *(const uint4*)&ll[0];
    *(uint4*)(Atl + off + 8) = *(const uint4*)&ll[8];
  }
}

__global__ __launch_bounds__(512) void k_outA(const U16* __restrict__ Kp,
                                              const U16* __restrict__ Ath, const U16* __restrict__ Atl,
                                              const float* __restrict__ u, float* __restrict__ outA){
  __shared__ U16 Ks[128][40];
  __shared__ U16 Ah[192][40];
  __shared__ U16 Al[192][40];
  const int t = threadIdx.x;
  const int i0 = blockIdx.y*128, d0 = blockIdx.x*192;
  const int w  = t >> 6, lane = t & 63;
  const int wm = w >> 1, wn = w & 1;
  const int l15 = lane & 15, lhi = lane >> 4;
  f32x4 acc[2][6];
  #pragma unroll
  for (int fm=0;fm<2;++fm)
    #pragma unroll
    for (int fn=0;fn<6;++fn) acc[fm][fn] = (f32x4){0.f,0.f,0.f,0.f};

  const int sr = t >> 2, sseg = t & 3;
  for (int j0 = 0; j0 < NN; j0 += 32){
    __syncthreads();
    {
      uint4 kw = *(const uint4*)(Kp + (size_t)(i0+sr)*NN + j0 + sseg*8);
      *(uint4*)&Ks[sr][sseg*8] = kw;
      #pragma unroll
      for (int uu=0; uu<3; ++uu){
        int id = t + 512*uu;
        if (id < 768){
          int r = id >> 2, seg = id & 3;
          uint4 aw = *(const uint4*)(Ath + (size_t)(d0+r)*NN + j0 + seg*8);
          *(uint4*)&Ah[r][seg*8] = aw;
        } else {
          int rid = id - 768;
          int r = rid >> 2, seg = rid & 3;
          uint4 aw = *(const uint4*)(Atl + (size_t)(d0+r)*NN + j0 + seg*8);
          *(uint4*)&Al[r][seg*8] = aw;
        }
      }
    }
    __syncthreads();
    short8 af[2];
    #pragma unroll
    for (int fm=0;fm<2;++fm)
      af[fm] = *(const short8*)&Ks[wm*32 + fm*16 + l15][lhi*8];
    #pragma unroll
    for (int fn=0;fn<6;++fn){
      short8 bh = *(const short8*)&Ah[wn*96 + fn*16 + l15][lhi*8];
      short8 bl = *(const short8*)&Al[wn*96 + fn*16 + l15][lhi*8];
      #pragma unroll
      for (int fm=0;fm<2;++fm){
        acc[fm][fn] = __builtin_amdgcn_mfma_f32_16x16x32_bf16(af[fm], bh, acc[fm][fn], 0, 0, 0);
        acc[fm][fn] = __builtin_amdgcn_mfma_f32_16x16x32_bf16(af[fm], bl, acc[fm][fn], 0, 0, 0);
      }
    }
  }
  float us[2][4];
  #pragma unroll
  for (int fm=0;fm<2;++fm)
    #pragma unroll
    for (int r=0;r<4;++r) us[fm][r] = u[i0 + wm*32 + fm*16 + lhi*4 + r];
  #pragma unroll
  for (int fm=0;fm<2;++fm)
    #pragma unroll
    for (int fn=0;fn<6;++fn)
      #pragma unroll
      for (int r=0;r<4;++r){
        int i = i0 + wm*32 + fm*16 + lhi*4 + r;
        int d = d0 + wn*96 + fn*16 + l15;
        outA[(size_t)i*DD + d] = acc[fm][fn][r] * us[fm][r];
      }
}

__global__ __launch_bounds__(256) void k_outB(const U16* __restrict__ Kp, const float* __restrict__ B,
                                              const float* __restrict__ u, const float* __restrict__ v,
                                              float* __restrict__ outB){
  __shared__ float Tt[64][65];
  const int t = threadIdx.x;
  const int j0t = blockIdx.y*64, d0 = blockIdx.x*128;
  const int jc = t & 63, ig = t >> 6;
  const int dg = t & 31, jg = t >> 5;
  float4 acc[8];
  #pragma unroll
  for (int m=0;m<8;m++) acc[m] = make_float4(0.f,0.f,0.f,0.f);
  for (int i0 = 0; i0 < NN; i0 += 64){
    __syncthreads();
    #pragma unroll
    for (int m=0;m<16;m++){
      int i = i0 + ig*16 + m;
      U32 kb = ((U32)Kp[(size_t)i*NN + j0t + jc]) << 16;
      Tt[jc][ig*16+m] = __uint_as_float(kb) * u[i];
    }
    __syncthreads();
    #pragma unroll 4
    for (int ii = 0; ii < 64; ++ii){
      float4 b4 = *(const float4*)(B + (size_t)(i0+ii)*DD + d0 + dg*4);
      #pragma unroll
      for (int m=0;m<8;m++){
        float tv = Tt[jg*8+m][ii];
        acc[m].x = fmaf(tv, b4.x, acc[m].x);
        acc[m].y = fmaf(tv, b4.y, acc[m].y);
        acc[m].z = fmaf(tv, b4.z, acc[m].z);
        acc[m].w = fmaf(tv, b4.w, acc[m].w);
      }
    }
  }
  #pragma unroll
  for (int m=0;m<8;m++){
    int j = j0t + jg*8 + m;
    float vj = v[j];
    acc[m].x *= vj; acc[m].y *= vj; acc[m].z *= vj; acc[m].w *= vj;
    *(float4*)(outB + (size_t)j*DD + d0 + dg*4) = acc[m];
  }
}

extern "C" void kernel_launch(void* const* d_in, const int* in_sizes, int n_in,
                              void* d_out, int out_size, void* d_ws, size_t ws_size,
                              hipStream_t stream) {
  const float* A = (const float*)d_in[0];
  const float* B = (const float*)d_in[1];
  float* out = (float*)d_out;
  char* ws = (char*)d_ws;
  U16*  q     = (U16*) (ws);                          // 134217728 B
  float* u    = (float*)(ws + 136314880);
  float* v    = (float*)(ws + 136347648);
  float* sqA  = (float*)(ws + 136380416);
  float* sqB  = (float*)(ws + 136413184);
  U32*  slots = (U32*) (ws + 136445952);
  float* part = (float*)(ws + 136511552);             // 1024*8192*4 = 33.5 MB (region proven in R7)
  // At scratch lives in d_out's second half (dead until k_outB writes it):
  U16* Ath = (U16*)(out + (size_t)NN*DD);
  U16* Atl = Ath + (size_t)NN*DD;

  k_init<<<1, 64, 0, stream>>>(slots);
  k_sqsum<<<4096, 256, 0, stream>>>(A, B, sqA, sqB, slots);
  k_dist<<<dim3(64,64), 256, 0, stream>>>(A, B, q, sqA, sqB, slots);
  k_buildK<<<32768, 256, 0, stream>>>((U32*)q, slots);

  const uint4* Kp4 = (const uint4*)q;
  k_fused<1><<<1024, 256, 0, stream>>>(Kp4, v, u, part);
  for (int it = 0; it < 200; ++it){
    k_vfin<<<256, 256, 0, stream>>>(part, v);
    k_fused<0><<<1024, 256, 0, stream>>>(Kp4, v, u, part);
  }

  k_At<<<dim3(12,128), 256, 0, stream>>>(A, v, Ath, Atl);
  k_outA<<<dim3(4,64), 512, 0, stream>>>(q, Ath, Atl, u, out);
  k_outB<<<dim3(6,128), 256, 0, stream>>>(q, B, u, v, out + (size_t)NN*DD);
}

// Round 14
// 9497.718 us; speedup vs baseline: 2.8800x; 1.3104x over previous
//
#include <hip/hip_runtime.h>
#include <stdint.h>

#define NN 8192
#define DD 768
#define LOG2E 1.4426950408889634f

typedef unsigned int  U32;
typedef unsigned short U16;
typedef __attribute__((ext_vector_type(8))) short short8;
typedef __attribute__((ext_vector_type(4))) float f32x4;

__device__ __forceinline__ U32 fkey(float x){
  U32 u = __float_as_uint(x);
  return (u & 0x80000000u) ? ~u : (u | 0x80000000u);
}
__device__ __forceinline__ float funkey(U32 k){
  return __uint_as_float((k & 0x80000000u) ? (k ^ 0x80000000u) : ~k);
}
__device__ __forceinline__ float ex2(float x){ return __builtin_amdgcn_exp2f(x); }
__device__ __forceinline__ float rcpf(float x){ return __builtin_amdgcn_rcpf(x); }
__device__ __forceinline__ float bflo(U32 w){ return __uint_as_float(w << 16); }
__device__ __forceinline__ float bfhi(U32 w){ return __uint_as_float(w & 0xFFFF0000u); }
__device__ __forceinline__ U16 tobf(float x){
  U32 a = __float_as_uint(x);
  return (U16)((a + 0x7FFFu + ((a >> 16) & 1u)) >> 16);
}
__device__ __forceinline__ U32 packbf(float lo, float hi){
  U32 a = __float_as_uint(lo), b = __float_as_uint(hi);
  a = a + 0x7FFFu + ((a >> 16) & 1u);
  b = b + 0x7FFFu + ((b >> 16) & 1u);
  return (a >> 16) | (b & 0xFFFF0000u);
}

// slots: 0 qmax 1 qmin 2 maxsqA key 3 maxsqB key
__global__ __launch_bounds__(64) void k_init(U32* slots){
  if (threadIdx.x == 0){ slots[0]=0u; slots[1]=0xFFFFFFFFu; slots[2]=0u; slots[3]=0u; }
}

__global__ __launch_bounds__(256) void k_sqsum(const float* __restrict__ A, const float* __restrict__ B,
                                               float* sqA, float* sqB, U32* slots){
  int wv = threadIdx.x >> 6, ln = threadIdx.x & 63;
  int row = blockIdx.x*4 + wv;
  const float* src = A; float* dst = sqA; U32* slot = slots + 2; int r = row;
  if (row >= NN){ src = B; dst = sqB; slot = slots + 3; r = row - NN; }
  const float* p = src + (size_t)r * DD;
  float s = 0.f;
  #pragma unroll
  for (int m = 0; m < DD/64; ++m){ float v = p[ln + 64*m]; s = fmaf(v, v, s); }
  #pragma unroll
  for (int o = 32; o; o >>= 1) s += __shfl_xor(s, o);
  if (ln == 0){ dst[r] = s; atomicMax(slot, fkey(s)); }
}

// 128x128 tile fp32 Gram -> dist -> u16 quantize; track qmax/qmin
__global__ __launch_bounds__(256) void k_dist(const float* __restrict__ A, const float* __restrict__ B,
                                              U16* __restrict__ q, const float* __restrict__ sqA,
                                              const float* __restrict__ sqB, U32* slots){
  __shared__ float As[16][128], Bs[16][128];
  __shared__ U32 redmx[4], redmn[4];
  const int t = threadIdx.x;
  const int i0 = blockIdx.y*128, j0 = blockIdx.x*128;
  const float S = 65535.f / (sqrtf(funkey(slots[2])) + sqrtf(funkey(slots[3])));
  float acc[8][8];
  #pragma unroll
  for (int m=0;m<8;m++)
    #pragma unroll
    for (int n=0;n<8;n++) acc[m][n] = 0.f;
  const int lr = t >> 1, lk = (t & 1)*8;
  const float* pa = A + (size_t)(i0+lr)*DD + lk;
  const float* pb = B + (size_t)(j0+lr)*DD + lk;
  const int tx = t & 15, ty = t >> 4;
  for (int k0 = 0; k0 < DD; k0 += 16){
    __syncthreads();
    float4 a0 = *(const float4*)(pa + k0);
    float4 a1 = *(const float4*)(pa + k0 + 4);
    float4 b0 = *(const float4*)(pb + k0);
    float4 b1 = *(const float4*)(pb + k0 + 4);
    As[lk+0][lr]=a0.x; As[lk+1][lr]=a0.y; As[lk+2][lr]=a0.z; As[lk+3][lr]=a0.w;
    As[lk+4][lr]=a1.x; As[lk+5][lr]=a1.y; As[lk+6][lr]=a1.z; As[lk+7][lr]=a1.w;
    Bs[lk+0][lr]=b0.x; Bs[lk+1][lr]=b0.y; Bs[lk+2][lr]=b0.z; Bs[lk+3][lr]=b0.w;
    Bs[lk+4][lr]=b1.x; Bs[lk+5][lr]=b1.y; Bs[lk+6][lr]=b1.z; Bs[lk+7][lr]=b1.w;
    __syncthreads();
    #pragma unroll
    for (int kk = 0; kk < 16; ++kk){
      float4 am0 = *(const float4*)&As[kk][ty*8];
      float4 am1 = *(const float4*)&As[kk][ty*8+4];
      float4 bn0 = *(const float4*)&Bs[kk][tx*8];
      float4 bn1 = *(const float4*)&Bs[kk][tx*8+4];
      float ar[8] = {am0.x,am0.y,am0.z,am0.w,am1.x,am1.y,am1.z,am1.w};
      float br[8] = {bn0.x,bn0.y,bn0.z,bn0.w,bn1.x,bn1.y,bn1.z,bn1.w};
      #pragma unroll
      for (int m=0;m<8;m++)
        #pragma unroll
        for (int n=0;n<8;n++) acc[m][n] = fmaf(ar[m], br[n], acc[m][n]);
    }
  }
  U32 bmax = 0u, bmin = 0xFFFFu;
  #pragma unroll
  for (int m=0;m<8;m++){
    int i = i0 + ty*8 + m;
    float sa = sqA[i];
    U16 pk[8] __attribute__((aligned(16)));
    #pragma unroll
    for (int n=0;n<8;n++){
      int j = j0 + tx*8 + n;
      float sq = sa + sqB[j] - 2.f*acc[m][n];
      float d = sqrtf(fmaxf(sq, 0.f));
      d = fmaxf(d, 1e-6f);
      U32 qv = (U32)rintf(d * S);
      if (qv > 65535u) qv = 65535u;
      bmax = bmax > qv ? bmax : qv;
      bmin = bmin < qv ? bmin : qv;
      pk[n] = (U16)qv;
    }
    *(uint4*)(q + (size_t)i*NN + j0 + tx*8) = *(const uint4*)pk;
  }
  #pragma unroll
  for (int o=32;o;o>>=1){
    U32 om = __shfl_xor(bmax, o); bmax = bmax > om ? bmax : om;
    U32 on = __shfl_xor(bmin, o); bmin = bmin < on ? bmin : on;
  }
  if ((t & 63) == 0){ redmx[t>>6] = bmax; redmn[t>>6] = bmin; }
  __syncthreads();
  if (t == 0){
    U32 mx = redmx[0], mn = redmn[0];
    #pragma unroll
    for (int i=1;i<4;i++){ mx = mx > redmx[i] ? mx : redmx[i]; mn = mn < redmn[i] ? mn : redmn[i]; }
    atomicMax(slots+0, mx); atomicMin(slots+1, mn);
  }
}

// in-place u16 q -> bf16 K' = exp(logK + s), s = 50(1+qmin/qmax) ln-units
__global__ __launch_bounds__(256) void k_buildK(U32* K2, const U32* __restrict__ slots){
  const float qmaxf = (float)slots[0];
  const float r0n = (float)slots[1] / qmaxf;
  const float k1 = -100.f*LOG2E/qmaxf;
  const float c2 = 50.f*(1.f + r0n)*LOG2E;
  const float tcl = -1e-4f*LOG2E;
  size_t base = ((size_t)blockIdx.x*256 + threadIdx.x)*4;
  uint4 w = *(uint4*)(K2 + base);
  U32 r[4];
  U32 in[4] = {w.x, w.y, w.z, w.w};
  #pragma unroll
  for (int k=0;k<4;++k){
    float ql = (float)(in[k] & 0xFFFFu);
    float qh = (float)(in[k] >> 16);
    float el = ex2(fminf(ql*k1, tcl) + c2);
    float eh = ex2(fminf(qh*k1, tcl) + c2);
    r[k] = packbf(el, eh);
  }
  *(uint4*)(K2 + base) = make_uint4(r[0], r[1], r[2], r[3]);
}

// ---------------- fused Sinkhorn sweep (R13-proven; part now bf16-packed) ----------------
// 1024 blocks x 256 thr. Block rc owns rows [8rc, 8rc+8); thread owns 32 cols.
template<int FIRST>
__global__ __launch_bounds__(256) void k_fused(const uint4* __restrict__ Kp,
                                               const float* __restrict__ v,
                                               float* __restrict__ u,
                                               U32* __restrict__ partb){
  __shared__ float4 vl4[2048];          // 32 KB
  __shared__ float ws[2][4][4];
  const int t = threadIdx.x;
  const int rc = blockIdx.x;
  const int r0 = rc*8;
  const int wv = t >> 6, ln = t & 63;
  if (!FIRST){
    #pragma unroll
    for (int h = 0; h < 8; ++h){
      int V = t + 256*h;
      vl4[V ^ ((V >> 3) & 7)] = ((const float4*)v)[V];
    }
    __syncthreads();
  }
  float a[4][8];
  #pragma unroll
  for (int s=0;s<4;++s)
    #pragma unroll
    for (int e=0;e<8;++e) a[s][e] = 0.f;

  #pragma unroll
  for (int g=0; g<2; ++g){
    uint4 kw[4][4];                     // [row in group][strip]
    #pragma unroll
    for (int rr=0; rr<4; ++rr)
      #pragma unroll
      for (int s=0; s<4; ++s)
        kw[rr][s] = Kp[(size_t)(r0 + g*4 + rr)*1024 + s*256 + t];
    float uu[4];
    if (!FIRST){
      float d[4] = {0.f,0.f,0.f,0.f};
      #pragma unroll
      for (int s=0; s<4; ++s){
        int V = (s*256 + t)*2;
        int msk = (V >> 3) & 7;         // same for V and V+1 (V even)
        float4 v0 = vl4[V ^ msk];
        float4 v1 = vl4[(V + 1) ^ msk];
        #pragma unroll
        for (int rr=0; rr<4; ++rr){
          uint4 w = kw[rr][s];
          d[rr]=fmaf(bflo(w.x),v0.x,d[rr]); d[rr]=fmaf(bfhi(w.x),v0.y,d[rr]);
          d[rr]=fmaf(bflo(w.y),v0.z,d[rr]); d[rr]=fmaf(bfhi(w.y),v0.w,d[rr]);
          d[rr]=fmaf(bflo(w.z),v1.x,d[rr]); d[rr]=fmaf(bfhi(w.z),v1.y,d[rr]);
          d[rr]=fmaf(bflo(w.w),v1.z,d[rr]); d[rr]=fmaf(bfhi(w.w),v1.w,d[rr]);
        }
      }
      #pragma unroll
      for (int o=32; o; o>>=1){
        #pragma unroll
        for (int rr=0; rr<4; ++rr) d[rr] += __shfl_xor(d[rr], o);
      }
      if (ln == 0){
        #pragma unroll
        for (int rr=0; rr<4; ++rr) ws[g & 1][rr][wv] = d[rr];
      }
      __syncthreads();
      #pragma unroll
      for (int rr=0; rr<4; ++rr)
        uu[rr] = rcpf(ws[g&1][rr][0] + ws[g&1][rr][1] + ws[g&1][rr][2] + ws[g&1][rr][3]);
    } else {
      #pragma unroll
      for (int rr=0; rr<4; ++rr) uu[rr] = 1.0f/8192.0f;
    }
    if (t < 4) u[r0 + g*4 + t] = uu[t];
    #pragma unroll
    for (int rr=0; rr<4; ++rr){
      float ur = uu[rr];
      #pragma unroll
      for (int s=0; s<4; ++s){
        uint4 w = kw[rr][s];
        a[s][0]=fmaf(bflo(w.x),ur,a[s][0]); a[s][1]=fmaf(bfhi(w.x),ur,a[s][1]);
        a[s][2]=fmaf(bflo(w.y),ur,a[s][2]); a[s][3]=fmaf(bfhi(w.y),ur,a[s][3]);
        a[s][4]=fmaf(bflo(w.z),ur,a[s][4]); a[s][5]=fmaf(bfhi(w.z),ur,a[s][5]);
        a[s][6]=fmaf(bflo(w.w),ur,a[s][6]); a[s][7]=fmaf(bfhi(w.w),ur,a[s][7]);
      }
    }
  }
  #pragma unroll
  for (int s=0; s<4; ++s){
    U32* pp = partb + (size_t)rc*4096 + (s*256 + t)*4;
    *(uint4*)pp = make_uint4(packbf(a[s][0],a[s][1]), packbf(a[s][2],a[s][3]),
                             packbf(a[s][4],a[s][5]), packbf(a[s][6],a[s][7]));
  }
}

// v[c] = 1 / sum over 1024 bf16-packed chunks. Block covers 16 U32-words (32 cols).
__global__ __launch_bounds__(256) void k_vfin(const U32* __restrict__ partb, float* __restrict__ v){
  __shared__ float red[16][16][2];
  const int t = threadIdx.x;
  const int pr = t & 15, kk = t >> 4;   // pr: word, kk: chunk-group (16 x 64 chunks)
  const int cw = blockIdx.x*16 + pr;
  float s0 = 0.f, s1 = 0.f;
  #pragma unroll 8
  for (int m = 0; m < 64; ++m){
    U32 w = partb[(size_t)(kk*64 + m)*4096 + cw];
    s0 += bflo(w); s1 += bfhi(w);
  }
  red[pr][kk][0] = s0; red[pr][kk][1] = s1;
  __syncthreads();
  if (t < 32){
    int p2 = t >> 1, hf = t & 1;
    float s = 0.f;
    #pragma unroll
    for (int k=0;k<16;++k) s += red[p2][k][hf];
    v[blockIdx.x*32 + p2*2 + hf] = rcpf(s);
  }
}

// ---------------- epilogue ----------------
// Xt_h/Xt_l[d][r] = bf16 hi/lo split of s_r * X[r][d]  (transposed, r-fast)
__global__ __launch_bounds__(256) void k_At(const float* __restrict__ X, const float* __restrict__ sc,
                                            U16* __restrict__ Xth, U16* __restrict__ Xtl){
  __shared__ float Ts[64][65];
  const int t = threadIdx.x;
  const int d0 = blockIdx.x*64, j0 = blockIdx.y*64;
  {
    const int r = t >> 2, cs = (t & 3)*16;
    const float vj = sc[j0 + r];
    #pragma unroll
    for (int e=0;e<4;++e){
      float4 a4 = *(const float4*)(X + (size_t)(j0+r)*DD + d0 + cs + e*4);
      Ts[r][cs+e*4+0]=a4.x*vj; Ts[r][cs+e*4+1]=a4.y*vj;
      Ts[r][cs+e*4+2]=a4.z*vj; Ts[r][cs+e*4+3]=a4.w*vj;
    }
  }
  __syncthreads();
  {
    const int dr = t >> 2, jseg = t & 3;
    U16 hh[16], ll[16];
    #pragma unroll
    for (int e=0;e<16;++e){
      float x = Ts[jseg*16+e][dr];
      U16 h = tobf(x);
      hh[e] = h;
      ll[e] = tobf(x - __uint_as_float(((U32)h) << 16));
    }
    size_t off = (size_t)(d0+dr)*NN + j0 + jseg*16;
    *(uint4*)(Xth + off)     = *(const uint4*)&hh[0];
    *(uint4*)(Xth + off + 8) = *(const uint4*)&hh[8];
    *(uint4*)(Xtl + off)     = *(const uint4*)&ll[0];
    *(uint4*)(Xtl + off + 8) = *(const uint4*)&ll[8];
  }
}

// MFMA: aligned_A[i][d] = u_i * sum_j K'[i][j] * (At_h+At_l)[d][j]   (verified R6/R8)
__global__ __launch_bounds__(512) void k_outA(const U16* __restrict__ Kp,
                                              const U16* __restrict__ Ath, const U16* __restrict__ Atl,
                                              const float* __restrict__ u, float* __restrict__ outA){
  __shared__ U16 Ks[128][40];
  __shared__ U16 Ah[192][40];
  __shared__ U16 Al[192][40];
  const int t = threadIdx.x;
  const int i0 = blockIdx.y*128, d0 = blockIdx.x*192;
  const int w  = t >> 6, lane = t & 63;
  const int wm = w >> 1, wn = w & 1;
  const int l15 = lane & 15, lhi = lane >> 4;
  f32x4 acc[2][6];
  #pragma unroll
  for (int fm=0;fm<2;++fm)
    #pragma unroll
    for (int fn=0;fn<6;++fn) acc[fm][fn] = (f32x4){0.f,0.f,0.f,0.f};

  const int sr = t >> 2, sseg = t & 3;
  for (int j0 = 0; j0 < NN; j0 += 32){
    __syncthreads();
    {
      uint4 kw = *(const uint4*)(Kp + (size_t)(i0+sr)*NN + j0 + sseg*8);
      *(uint4*)&Ks[sr][sseg*8] = kw;
      #pragma unroll
      for (int uu=0; uu<3; ++uu){
        int id = t + 512*uu;
        if (id < 768){
          int r = id >> 2, seg = id & 3;
          uint4 aw = *(const uint4*)(Ath + (size_t)(d0+r)*NN + j0 + seg*8);
          *(uint4*)&Ah[r][seg*8] = aw;
        } else {
          int rid = id - 768;
          int r = rid >> 2, seg = rid & 3;
          uint4 aw = *(const uint4*)(Atl + (size_t)(d0+r)*NN + j0 + seg*8);
          *(uint4*)&Al[r][seg*8] = aw;
        }
      }
    }
    __syncthreads();
    short8 af[2];
    #pragma unroll
    for (int fm=0;fm<2;++fm)
      af[fm] = *(const short8*)&Ks[wm*32 + fm*16 + l15][lhi*8];
    #pragma unroll
    for (int fn=0;fn<6;++fn){
      short8 bh = *(const short8*)&Ah[wn*96 + fn*16 + l15][lhi*8];
      short8 bl = *(const short8*)&Al[wn*96 + fn*16 + l15][lhi*8];
      #pragma unroll
      for (int fm=0;fm<2;++fm){
        acc[fm][fn] = __builtin_amdgcn_mfma_f32_16x16x32_bf16(af[fm], bh, acc[fm][fn], 0, 0, 0);
        acc[fm][fn] = __builtin_amdgcn_mfma_f32_16x16x32_bf16(af[fm], bl, acc[fm][fn], 0, 0, 0);
      }
    }
  }
  float us[2][4];
  #pragma unroll
  for (int fm=0;fm<2;++fm)
    #pragma unroll
    for (int r=0;r<4;++r) us[fm][r] = u[i0 + wm*32 + fm*16 + lhi*4 + r];
  #pragma unroll
  for (int fm=0;fm<2;++fm)
    #pragma unroll
    for (int fn=0;fn<6;++fn)
      #pragma unroll
      for (int r=0;r<4;++r){
        int i = i0 + wm*32 + fm*16 + lhi*4 + r;
        int d = d0 + wn*96 + fn*16 + l15;
        outA[(size_t)i*DD + d] = acc[fm][fn][r] * us[fm][r];
      }
}

// MFMA mirror: aligned_B[j][d] = v_j * sum_i K'[i][j] * (Bt_h+Bt_l)[d][i]
// A-operand = K'^T staged via in-LDS transpose (Kt[j][i]); B-operand from Bt (= u_i B[i][d], split).
__global__ __launch_bounds__(512) void k_outBm(const U16* __restrict__ Kp,
                                               const U16* __restrict__ Bth, const U16* __restrict__ Btl,
                                               const float* __restrict__ v, float* __restrict__ outB){
  __shared__ U16 Kt[128][40];
  __shared__ U16 Bh[192][40];
  __shared__ U16 Bl[192][40];
  const int t = threadIdx.x;
  const int j0 = blockIdx.y*128, d0 = blockIdx.x*192;
  const int w  = t >> 6, lane = t & 63;
  const int wm = w >> 1, wn = w & 1;
  const int l15 = lane & 15, lhi = lane >> 4;
  f32x4 acc[2][6];
  #pragma unroll
  for (int fm=0;fm<2;++fm)
    #pragma unroll
    for (int fn=0;fn<6;++fn) acc[fm][fn] = (f32x4){0.f,0.f,0.f,0.f};

  const int i_l = t & 31, jseg = t >> 5;    // K'^T staging: 32 i-rows x 16 jsegs(8 j each)
  for (int i0k = 0; i0k < NN; i0k += 32){
    __syncthreads();
    {
      uint4 kw = *(const uint4*)(Kp + (size_t)(i0k+i_l)*NN + j0 + jseg*8);
      const U16* pk = (const U16*)&kw;
      #pragma unroll
      for (int e=0;e<8;++e) Kt[jseg*8+e][i_l] = pk[e];
      #pragma unroll
      for (int uu=0; uu<3; ++uu){
        int id = t + 512*uu;
        if (id < 768){
          int r = id >> 2, seg = id & 3;
          uint4 bw = *(const uint4*)(Bth + (size_t)(d0+r)*NN + i0k + seg*8);
          *(uint4*)&Bh[r][seg*8] = bw;
        } else {
          int rid = id - 768;
          int r = rid >> 2, seg = rid & 3;
          uint4 bw = *(const uint4*)(Btl + (size_t)(d0+r)*NN + i0k + seg*8);
          *(uint4*)&Bl[r][seg*8] = bw;
        }
      }
    }
    __syncthreads();
    short8 af[2];
    #pragma unroll
    for (int fm=0;fm<2;++fm)
      af[fm] = *(const short8*)&Kt[wm*32 + fm*16 + l15][lhi*8];
    #pragma unroll
    for (int fn=0;fn<6;++fn){
      short8 bh = *(const short8*)&Bh[wn*96 + fn*16 + l15][lhi*8];
      short8 bl = *(const short8*)&Bl[wn*96 + fn*16 + l15][lhi*8];
      #pragma unroll
      for (int fm=0;fm<2;++fm){
        acc[fm][fn] = __builtin_amdgcn_mfma_f32_16x16x32_bf16(af[fm], bh, acc[fm][fn], 0, 0, 0);
        acc[fm][fn] = __builtin_amdgcn_mfma_f32_16x16x32_bf16(af[fm], bl, acc[fm][fn], 0, 0, 0);
      }
    }
  }
  float vs[2][4];
  #pragma unroll
  for (int fm=0;fm<2;++fm)
    #pragma unroll
    for (int r=0;r<4;++r) vs[fm][r] = v[j0 + wm*32 + fm*16 + lhi*4 + r];
  #pragma unroll
  for (int fm=0;fm<2;++fm)
    #pragma unroll
    for (int fn=0;fn<6;++fn)
      #pragma unroll
      for (int r=0;r<4;++r){
        int j = j0 + wm*32 + fm*16 + lhi*4 + r;
        int d = d0 + wn*96 + fn*16 + l15;
        outB[(size_t)j*DD + d] = acc[fm][fn][r] * vs[fm][r];
      }
}

extern "C" void kernel_launch(void* const* d_in, const int* in_sizes, int n_in,
                              void* d_out, int out_size, void* d_ws, size_t ws_size,
                              hipStream_t stream) {
  const float* A = (const float*)d_in[0];
  const float* B = (const float*)d_in[1];
  float* out = (float*)d_out;
  char* ws = (char*)d_ws;
  U16*  q     = (U16*) (ws);                          // 134217728 B
  float* u    = (float*)(ws + 136314880);
  float* v    = (float*)(ws + 136347648);
  float* sqA  = (float*)(ws + 136380416);
  float* sqB  = (float*)(ws + 136413184);
  U32*  slots = (U32*) (ws + 136445952);
  U32*  partb = (U32*) (ws + 136511552);              // 1024*4096*4 = 16.8 MB bf16-packed
  // Bt split buffers reuse the part region post-loop (<= 33.5 MB proven writable in R13):
  U16* Bth = (U16*)(ws + 136511552);
  U16* Btl = Bth + (size_t)NN*DD;
  // At scratch lives in d_out's second half (dead until k_outBm writes it):
  U16* Ath = (U16*)(out + (size_t)NN*DD);
  U16* Atl = Ath + (size_t)NN*DD;

  k_init<<<1, 64, 0, stream>>>(slots);
  k_sqsum<<<4096, 256, 0, stream>>>(A, B, sqA, sqB, slots);
  k_dist<<<dim3(64,64), 256, 0, stream>>>(A, B, q, sqA, sqB, slots);
  k_buildK<<<32768, 256, 0, stream>>>((U32*)q, slots);

  const uint4* Kp4 = (const uint4*)q;
  k_fused<1><<<1024, 256, 0, stream>>>(Kp4, v, u, partb);
  for (int it = 0; it < 200; ++it){
    k_vfin<<<256, 256, 0, stream>>>(partb, v);
    k_fused<0><<<1024, 256, 0, stream>>>(Kp4, v, u, partb);
  }

  k_At<<<dim3(12,128), 256, 0, stream>>>(A, v, Ath, Atl);
  k_outA<<<dim3(4,64), 512, 0, stream>>>(q, Ath, Atl, u, out);
  k_At<<<dim3(12,128), 256, 0, stream>>>(B, u, Bth, Btl);
  k_outBm<<<dim3(4,64), 512, 0, stream>>>(q, Bth, Btl, v, out + (size_t)NN*DD);
}

// Round 15
// 8683.722 us; speedup vs baseline: 3.1499x; 1.0937x over previous
//
#include <hip/hip_runtime.h>
#include <stdint.h>

#define NN 8192
#define DD 768
#define LOG2E 1.4426950408889634f

typedef unsigned int  U32;
typedef unsigned short U16;
typedef __attribute__((ext_vector_type(8))) short short8;
typedef __attribute__((ext_vector_type(4))) float f32x4;

__device__ __forceinline__ U32 fkey(float x){
  U32 u = __float_as_uint(x);
  return (u & 0x80000000u) ? ~u : (u | 0x80000000u);
}
__device__ __forceinline__ float funkey(U32 k){
  return __uint_as_float((k & 0x80000000u) ? (k ^ 0x80000000u) : ~k);
}
__device__ __forceinline__ float ex2(float x){ return __builtin_amdgcn_exp2f(x); }
__device__ __forceinline__ float rcpf(float x){ return __builtin_amdgcn_rcpf(x); }
__device__ __forceinline__ float bflo(U32 w){ return __uint_as_float(w << 16); }
__device__ __forceinline__ float bfhi(U32 w){ return __uint_as_float(w & 0xFFFF0000u); }
__device__ __forceinline__ U16 tobf(float x){
  U32 a = __float_as_uint(x);
  return (U16)((a + 0x7FFFu + ((a >> 16) & 1u)) >> 16);
}
__device__ __forceinline__ U32 packbf(float lo, float hi){
  U32 a = __float_as_uint(lo), b = __float_as_uint(hi);
  a = a + 0x7FFFu + ((a >> 16) & 1u);
  b = b + 0x7FFFu + ((b >> 16) & 1u);
  return (a >> 16) | (b & 0xFFFF0000u);
}

// slots: 0 qmax 1 qmin 2 maxsqA key 3 maxsqB key
__global__ __launch_bounds__(64) void k_init(U32* slots){
  if (threadIdx.x == 0){ slots[0]=0u; slots[1]=0xFFFFFFFFu; slots[2]=0u; slots[3]=0u; }
}

__global__ __launch_bounds__(256) void k_sqsum(const float* __restrict__ A, const float* __restrict__ B,
                                               float* sqA, float* sqB, U32* slots){
  int wv = threadIdx.x >> 6, ln = threadIdx.x & 63;
  int row = blockIdx.x*4 + wv;
  const float* src = A; float* dst = sqA; U32* slot = slots + 2; int r = row;
  if (row >= NN){ src = B; dst = sqB; slot = slots + 3; r = row - NN; }
  const float* p = src + (size_t)r * DD;
  float s = 0.f;
  #pragma unroll
  for (int m = 0; m < DD/64; ++m){ float v = p[ln + 64*m]; s = fmaf(v, v, s); }
  #pragma unroll
  for (int o = 32; o; o >>= 1) s += __shfl_xor(s, o);
  if (ln == 0){ dst[r] = s; atomicMax(slot, fkey(s)); }
}

// MFMA distance kernel: G = A.B^T via bf16 hi/lo split (hh + hl + lh), then
// d = sqrt(max(sqA+sqB-2G,0)) -> clamp -> u16 quantize; min/max tracked.
// 128x128 tile, 512 thr = 8 waves (4m x 2n); K-step 32 over DD=768.
__global__ __launch_bounds__(512) void k_distm(const float* __restrict__ A, const float* __restrict__ B,
                                               U16* __restrict__ q, const float* __restrict__ sqA,
                                               const float* __restrict__ sqB, U32* slots){
  __shared__ U16 Ahs[128][40], Als[128][40];
  __shared__ U16 Bhs[128][40], Bls[128][40];
  __shared__ U32 redmx[8], redmn[8];
  const int t = threadIdx.x;
  const int i0 = blockIdx.y*128, j0 = blockIdx.x*128;
  const float S = 65535.f / (sqrtf(funkey(slots[2])) + sqrtf(funkey(slots[3])));
  const int w = t >> 6, lane = t & 63;
  const int wm = w >> 1, wn = w & 1;
  const int l15 = lane & 15, lhi = lane >> 4;
  f32x4 acc[2][4];
  #pragma unroll
  for (int fm=0;fm<2;++fm)
    #pragma unroll
    for (int fn=0;fn<4;++fn) acc[fm][fn] = (f32x4){0.f,0.f,0.f,0.f};

  const int sr = t >> 2, sseg = t & 3;
  for (int k0 = 0; k0 < DD; k0 += 32){
    __syncthreads();
    {
      const float* pa = A + (size_t)(i0+sr)*DD + k0 + sseg*8;
      const float* pb = B + (size_t)(j0+sr)*DD + k0 + sseg*8;
      float4 a0 = *(const float4*)pa;
      float4 a1 = *(const float4*)(pa+4);
      float4 b0 = *(const float4*)pb;
      float4 b1 = *(const float4*)(pb+4);
      float av[8] = {a0.x,a0.y,a0.z,a0.w,a1.x,a1.y,a1.z,a1.w};
      float bv[8] = {b0.x,b0.y,b0.z,b0.w,b1.x,b1.y,b1.z,b1.w};
      U16 ah[8], al[8], bh[8], bl[8];
      #pragma unroll
      for (int e=0;e<8;++e){
        U16 h = tobf(av[e]); ah[e] = h;
        al[e] = tobf(av[e] - __uint_as_float(((U32)h)<<16));
        U16 g = tobf(bv[e]); bh[e] = g;
        bl[e] = tobf(bv[e] - __uint_as_float(((U32)g)<<16));
      }
      *(uint4*)&Ahs[sr][sseg*8] = *(const uint4*)ah;
      *(uint4*)&Als[sr][sseg*8] = *(const uint4*)al;
      *(uint4*)&Bhs[sr][sseg*8] = *(const uint4*)bh;
      *(uint4*)&Bls[sr][sseg*8] = *(const uint4*)bl;
    }
    __syncthreads();
    short8 fah[2], fal[2];
    #pragma unroll
    for (int fm=0;fm<2;++fm){
      fah[fm] = *(const short8*)&Ahs[wm*32 + fm*16 + l15][lhi*8];
      fal[fm] = *(const short8*)&Als[wm*32 + fm*16 + l15][lhi*8];
    }
    #pragma unroll
    for (int fn=0;fn<4;++fn){
      short8 fbh = *(const short8*)&Bhs[wn*64 + fn*16 + l15][lhi*8];
      short8 fbl = *(const short8*)&Bls[wn*64 + fn*16 + l15][lhi*8];
      #pragma unroll
      for (int fm=0;fm<2;++fm){
        acc[fm][fn] = __builtin_amdgcn_mfma_f32_16x16x32_bf16(fah[fm], fbh, acc[fm][fn], 0, 0, 0);
        acc[fm][fn] = __builtin_amdgcn_mfma_f32_16x16x32_bf16(fah[fm], fbl, acc[fm][fn], 0, 0, 0);
        acc[fm][fn] = __builtin_amdgcn_mfma_f32_16x16x32_bf16(fal[fm], fbh, acc[fm][fn], 0, 0, 0);
      }
    }
  }
  U32 bmax = 0u, bmin = 0xFFFFu;
  #pragma unroll
  for (int fm=0;fm<2;++fm){
    #pragma unroll
    for (int fn=0;fn<4;++fn){
      int j = j0 + wn*64 + fn*16 + l15;
      float sb = sqB[j];
      #pragma unroll
      for (int r=0;r<4;++r){
        int i = i0 + wm*32 + fm*16 + lhi*4 + r;
        float sq = sqA[i] + sb - 2.f*acc[fm][fn][r];
        float d = sqrtf(fmaxf(sq, 0.f));
        d = fmaxf(d, 1e-6f);
        U32 qv = (U32)rintf(d * S);
        if (qv > 65535u) qv = 65535u;
        bmax = bmax > qv ? bmax : qv;
        bmin = bmin < qv ? bmin : qv;
        q[(size_t)i*NN + j] = (U16)qv;
      }
    }
  }
  #pragma unroll
  for (int o=32;o;o>>=1){
    U32 om = __shfl_xor(bmax, o); bmax = bmax > om ? bmax : om;
    U32 on = __shfl_xor(bmin, o); bmin = bmin < on ? bmin : on;
  }
  if (lane == 0){ redmx[w] = bmax; redmn[w] = bmin; }
  __syncthreads();
  if (t == 0){
    U32 mx = redmx[0], mn = redmn[0];
    #pragma unroll
    for (int i=1;i<8;i++){ mx = mx > redmx[i] ? mx : redmx[i]; mn = mn < redmn[i] ? mn : redmn[i]; }
    atomicMax(slots+0, mx); atomicMin(slots+1, mn);
  }
}

// in-place u16 q -> bf16 K' = exp(logK + s), s = 50(1+qmin/qmax) ln-units
__global__ __launch_bounds__(256) void k_buildK(U32* K2, const U32* __restrict__ slots){
  const float qmaxf = (float)slots[0];
  const float r0n = (float)slots[1] / qmaxf;
  const float k1 = -100.f*LOG2E/qmaxf;
  const float c2 = 50.f*(1.f + r0n)*LOG2E;
  const float tcl = -1e-4f*LOG2E;
  size_t base = ((size_t)blockIdx.x*256 + threadIdx.x)*4;
  uint4 w = *(uint4*)(K2 + base);
  U32 r[4];
  U32 in[4] = {w.x, w.y, w.z, w.w};
  #pragma unroll
  for (int k=0;k<4;++k){
    float ql = (float)(in[k] & 0xFFFFu);
    float qh = (float)(in[k] >> 16);
    float el = ex2(fminf(ql*k1, tcl) + c2);
    float eh = ex2(fminf(qh*k1, tcl) + c2);
    r[k] = packbf(el, eh);
  }
  *(uint4*)(K2 + base) = make_uint4(r[0], r[1], r[2], r[3]);
}

// ---------------- fused Sinkhorn sweep (v in registers; bf16-packed part) ----------------
// 1024 blocks x 256 thr. Block rc owns rows [8rc, 8rc+8); thread owns 32 cols.
template<int FIRST>
__global__ __launch_bounds__(256) void k_fused(const uint4* __restrict__ Kp,
                                               const float* __restrict__ v,
                                               float* __restrict__ u,
                                               U32* __restrict__ partb){
  __shared__ float ws[2][4][4];
  const int t = threadIdx.x;
  const int rc = blockIdx.x;
  const int r0 = rc*8;
  const int wv = t >> 6, ln = t & 63;
  float4 vr[4][2];
  if (!FIRST){
    #pragma unroll
    for (int s=0;s<4;++s){
      vr[s][0] = *(const float4*)(v + s*2048 + t*8);
      vr[s][1] = *(const float4*)(v + s*2048 + t*8 + 4);
    }
  }
  float a[4][8];
  #pragma unroll
  for (int s=0;s<4;++s)
    #pragma unroll
    for (int e=0;e<8;++e) a[s][e] = 0.f;

  #pragma unroll
  for (int g=0; g<2; ++g){
    uint4 kw[4][4];                     // [row in group][strip]
    #pragma unroll
    for (int rr=0; rr<4; ++rr)
      #pragma unroll
      for (int s=0; s<4; ++s)
        kw[rr][s] = Kp[(size_t)(r0 + g*4 + rr)*1024 + s*256 + t];
    float uu[4];
    if (!FIRST){
      float d[4] = {0.f,0.f,0.f,0.f};
      #pragma unroll
      for (int s=0; s<4; ++s){
        float4 v0 = vr[s][0];
        float4 v1 = vr[s][1];
        #pragma unroll
        for (int rr=0; rr<4; ++rr){
          uint4 w = kw[rr][s];
          d[rr]=fmaf(bflo(w.x),v0.x,d[rr]); d[rr]=fmaf(bfhi(w.x),v0.y,d[rr]);
          d[rr]=fmaf(bflo(w.y),v0.z,d[rr]); d[rr]=fmaf(bfhi(w.y),v0.w,d[rr]);
          d[rr]=fmaf(bflo(w.z),v1.x,d[rr]); d[rr]=fmaf(bfhi(w.z),v1.y,d[rr]);
          d[rr]=fmaf(bflo(w.w),v1.z,d[rr]); d[rr]=fmaf(bfhi(w.w),v1.w,d[rr]);
        }
      }
      #pragma unroll
      for (int o=32; o; o>>=1){
        #pragma unroll
        for (int rr=0; rr<4; ++rr) d[rr] += __shfl_xor(d[rr], o);
      }
      if (ln == 0){
        #pragma unroll
        for (int rr=0; rr<4; ++rr) ws[g & 1][rr][wv] = d[rr];
      }
      __syncthreads();
      #pragma unroll
      for (int rr=0; rr<4; ++rr)
        uu[rr] = rcpf(ws[g&1][rr][0] + ws[g&1][rr][1] + ws[g&1][rr][2] + ws[g&1][rr][3]);
    } else {
      #pragma unroll
      for (int rr=0; rr<4; ++rr) uu[rr] = 1.0f/8192.0f;
    }
    if (t < 4) u[r0 + g*4 + t] = uu[t];
    #pragma unroll
    for (int rr=0; rr<4; ++rr){
      float ur = uu[rr];
      #pragma unroll
      for (int s=0; s<4; ++s){
        uint4 w = kw[rr][s];
        a[s][0]=fmaf(bflo(w.x),ur,a[s][0]); a[s][1]=fmaf(bfhi(w.x),ur,a[s][1]);
        a[s][2]=fmaf(bflo(w.y),ur,a[s][2]); a[s][3]=fmaf(bfhi(w.y),ur,a[s][3]);
        a[s][4]=fmaf(bflo(w.z),ur,a[s][4]); a[s][5]=fmaf(bfhi(w.z),ur,a[s][5]);
        a[s][6]=fmaf(bflo(w.w),ur,a[s][6]); a[s][7]=fmaf(bfhi(w.w),ur,a[s][7]);
      }
    }
  }
  #pragma unroll
  for (int s=0; s<4; ++s){
    U32* pp = partb + (size_t)rc*4096 + (s*256 + t)*4;
    *(uint4*)pp = make_uint4(packbf(a[s][0],a[s][1]), packbf(a[s][2],a[s][3]),
                             packbf(a[s][4],a[s][5]), packbf(a[s][6],a[s][7]));
  }
}

// v[c] = 1 / sum over 1024 bf16-packed chunks. Block covers 16 U32-words (32 cols).
__global__ __launch_bounds__(256) void k_vfin(const U32* __restrict__ partb, float* __restrict__ v){
  __shared__ float red[16][16][2];
  const int t = threadIdx.x;
  const int pr = t & 15, kk = t >> 4;   // pr: word, kk: chunk-group (16 x 64 chunks)
  const int cw = blockIdx.x*16 + pr;
  float s0 = 0.f, s1 = 0.f;
  #pragma unroll 8
  for (int m = 0; m < 64; ++m){
    U32 w = partb[(size_t)(kk*64 + m)*4096 + cw];
    s0 += bflo(w); s1 += bfhi(w);
  }
  red[pr][kk][0] = s0; red[pr][kk][1] = s1;
  __syncthreads();
  if (t < 32){
    int p2 = t >> 1, hf = t & 1;
    float s = 0.f;
    #pragma unroll
    for (int k=0;k<16;++k) s += red[p2][k][hf];
    v[blockIdx.x*32 + p2*2 + hf] = rcpf(s);
  }
}

// ---------------- epilogue ----------------
// Xt_h/Xt_l[d][r] = bf16 hi/lo split of s_r * X[r][d]  (transposed, r-fast)
__global__ __launch_bounds__(256) void k_At(const float* __restrict__ X, const float* __restrict__ sc,
                                            U16* __restrict__ Xth, U16* __restrict__ Xtl){
  __shared__ float Ts[64][65];
  const int t = threadIdx.x;
  const int d0 = blockIdx.x*64, j0 = blockIdx.y*64;
  {
    const int r = t >> 2, cs = (t & 3)*16;
    const float vj = sc[j0 + r];
    #pragma unroll
    for (int e=0;e<4;++e){
      float4 a4 = *(const float4*)(X + (size_t)(j0+r)*DD + d0 + cs + e*4);
      Ts[r][cs+e*4+0]=a4.x*vj; Ts[r][cs+e*4+1]=a4.y*vj;
      Ts[r][cs+e*4+2]=a4.z*vj; Ts[r][cs+e*4+3]=a4.w*vj;
    }
  }
  __syncthreads();
  {
    const int dr = t >> 2, jseg = t & 3;
    U16 hh[16], ll[16];
    #pragma unroll
    for (int e=0;e<16;++e){
      float x = Ts[jseg*16+e][dr];
      U16 h = tobf(x);
      hh[e] = h;
      ll[e] = tobf(x - __uint_as_float(((U32)h) << 16));
    }
    size_t off = (size_t)(d0+dr)*NN + j0 + jseg*16;
    *(uint4*)(Xth + off)     = *(const uint4*)&hh[0];
    *(uint4*)(Xth + off + 8) = *(const uint4*)&hh[8];
    *(uint4*)(Xtl + off)     = *(const uint4*)&ll[0];
    *(uint4*)(Xtl + off + 8) = *(const uint4*)&ll[8];
  }
}

// MFMA: aligned_A[i][d] = u_i * sum_j K'[i][j] * (At_h+At_l)[d][j]   (verified R6/R8)
__global__ __launch_bounds__(512) void k_outA(const U16* __restrict__ Kp,
                                              const U16* __restrict__ Ath, const U16* __restrict__ Atl,
                                              const float* __restrict__ u, float* __restrict__ outA){
  __shared__ U16 Ks[128][40];
  __shared__ U16 Ah[192][40];
  __shared__ U16 Al[192][40];
  const int t = threadIdx.x;
  const int i0 = blockIdx.y*128, d0 = blockIdx.x*192;
  const int w  = t >> 6, lane = t & 63;
  const int wm = w >> 1, wn = w & 1;
  const int l15 = lane & 15, lhi = lane >> 4;
  f32x4 acc[2][6];
  #pragma unroll
  for (int fm=0;fm<2;++fm)
    #pragma unroll
    for (int fn=0;fn<6;++fn) acc[fm][fn] = (f32x4){0.f,0.f,0.f,0.f};

  const int sr = t >> 2, sseg = t & 3;
  for (int j0 = 0; j0 < NN; j0 += 32){
    __syncthreads();
    {
      uint4 kw = *(const uint4*)(Kp + (size_t)(i0+sr)*NN + j0 + sseg*8);
      *(uint4*)&Ks[sr][sseg*8] = kw;
      #pragma unroll
      for (int uu=0; uu<3; ++uu){
        int id = t + 512*uu;
        if (id < 768){
          int r = id >> 2, seg = id & 3;
          uint4 aw = *(const uint4*)(Ath + (size_t)(d0+r)*NN + j0 + seg*8);
          *(uint4*)&Ah[r][seg*8] = aw;
        } else {
          int rid = id - 768;
          int r = rid >> 2, seg = rid & 3;
          uint4 aw = *(const uint4*)(Atl + (size_t)(d0+r)*NN + j0 + seg*8);
          *(uint4*)&Al[r][seg*8] = aw;
        }
      }
    }
    __syncthreads();
    short8 af[2];
    #pragma unroll
    for (int fm=0;fm<2;++fm)
      af[fm] = *(const short8*)&Ks[wm*32 + fm*16 + l15][lhi*8];
    #pragma unroll
    for (int fn=0;fn<6;++fn){
      short8 bh = *(const short8*)&Ah[wn*96 + fn*16 + l15][lhi*8];
      short8 bl = *(const short8*)&Al[wn*96 + fn*16 + l15][lhi*8];
      #pragma unroll
      for (int fm=0;fm<2;++fm){
        acc[fm][fn] = __builtin_amdgcn_mfma_f32_16x16x32_bf16(af[fm], bh, acc[fm][fn], 0, 0, 0);
        acc[fm][fn] = __builtin_amdgcn_mfma_f32_16x16x32_bf16(af[fm], bl, acc[fm][fn], 0, 0, 0);
      }
    }
  }
  float us[2][4];
  #pragma unroll
  for (int fm=0;fm<2;++fm)
    #pragma unroll
    for (int r=0;r<4;++r) us[fm][r] = u[i0 + wm*32 + fm*16 + lhi*4 + r];
  #pragma unroll
  for (int fm=0;fm<2;++fm)
    #pragma unroll
    for (int fn=0;fn<6;++fn)
      #pragma unroll
      for (int r=0;r<4;++r){
        int i = i0 + wm*32 + fm*16 + lhi*4 + r;
        int d = d0 + wn*96 + fn*16 + l15;
        outA[(size_t)i*DD + d] = acc[fm][fn][r] * us[fm][r];
      }
}

// MFMA mirror: aligned_B[j][d] = v_j * sum_i K'[i][j] * (Bt_h+Bt_l)[d][i]
__global__ __launch_bounds__(512) void k_outBm(const U16* __restrict__ Kp,
                                               const U16* __restrict__ Bth, const U16* __restrict__ Btl,
                                               const float* __restrict__ v, float* __restrict__ outB){
  __shared__ U16 Kt[128][40];
  __shared__ U16 Bh[192][40];
  __shared__ U16 Bl[192][40];
  const int t = threadIdx.x;
  const int j0 = blockIdx.y*128, d0 = blockIdx.x*192;
  const int w  = t >> 6, lane = t & 63;
  const int wm = w >> 1, wn = w & 1;
  const int l15 = lane & 15, lhi = lane >> 4;
  f32x4 acc[2][6];
  #pragma unroll
  for (int fm=0;fm<2;++fm)
    #pragma unroll
    for (int fn=0;fn<6;++fn) acc[fm][fn] = (f32x4){0.f,0.f,0.f,0.f};

  const int i_l = t & 31, jseg = t >> 5;    // K'^T staging: 32 i-rows x 16 jsegs(8 j each)
  for (int i0k = 0; i0k < NN; i0k += 32){
    __syncthreads();
    {
      uint4 kw = *(const uint4*)(Kp + (size_t)(i0k+i_l)*NN + j0 + jseg*8);
      const U16* pk = (const U16*)&kw;
      #pragma unroll
      for (int e=0;e<8;++e) Kt[jseg*8+e][i_l] = pk[e];
      #pragma unroll
      for (int uu=0; uu<3; ++uu){
        int id = t + 512*uu;
        if (id < 768){
          int r = id >> 2, seg = id & 3;
          uint4 bw = *(const uint4*)(Bth + (size_t)(d0+r)*NN + i0k + seg*8);
          *(uint4*)&Bh[r][seg*8] = bw;
        } else {
          int rid = id - 768;
          int r = rid >> 2, seg = rid & 3;
          uint4 bw = *(const uint4*)(Btl + (size_t)(d0+r)*NN + i0k + seg*8);
          *(uint4*)&Bl[r][seg*8] = bw;
        }
      }
    }
    __syncthreads();
    short8 af[2];
    #pragma unroll
    for (int fm=0;fm<2;++fm)
      af[fm] = *(const short8*)&Kt[wm*32 + fm*16 + l15][lhi*8];
    #pragma unroll
    for (int fn=0;fn<6;++fn){
      short8 bh = *(const short8*)&Bh[wn*96 + fn*16 + l15][lhi*8];
      short8 bl = *(const short8*)&Bl[wn*96 + fn*16 + l15][lhi*8];
      #pragma unroll
      for (int fm=0;fm<2;++fm){
        acc[fm][fn] = __builtin_amdgcn_mfma_f32_16x16x32_bf16(af[fm], bh, acc[fm][fn], 0, 0, 0);
        acc[fm][fn] = __builtin_amdgcn_mfma_f32_16x16x32_bf16(af[fm], bl, acc[fm][fn], 0, 0, 0);
      }
    }
  }
  float vs[2][4];
  #pragma unroll
  for (int fm=0;fm<2;++fm)
    #pragma unroll
    for (int r=0;r<4;++r) vs[fm][r] = v[j0 + wm*32 + fm*16 + lhi*4 + r];
  #pragma unroll
  for (int fm=0;fm<2;++fm)
    #pragma unroll
    for (int fn=0;fn<6;++fn)
      #pragma unroll
      for (int r=0;r<4;++r){
        int j = j0 + wm*32 + fm*16 + lhi*4 + r;
        int d = d0 + wn*96 + fn*16 + l15;
        outB[(size_t)j*DD + d] = acc[fm][fn][r] * vs[fm][r];
      }
}

extern "C" void kernel_launch(void* const* d_in, const int* in_sizes, int n_in,
                              void* d_out, int out_size, void* d_ws, size_t ws_size,
                              hipStream_t stream) {
  const float* A = (const float*)d_in[0];
  const float* B = (const float*)d_in[1];
  float* out = (float*)d_out;
  char* ws = (char*)d_ws;
  U16*  q     = (U16*) (ws);                          // 134217728 B
  float* u    = (float*)(ws + 136314880);
  float* v    = (float*)(ws + 136347648);
  float* sqA  = (float*)(ws + 136380416);
  float* sqB  = (float*)(ws + 136413184);
  U32*  slots = (U32*) (ws + 136445952);
  U32*  partb = (U32*) (ws + 136511552);              // 16.8 MB bf16-packed
  U16* Bth = (U16*)(ws + 136511552);                  // post-loop reuse of part region
  U16* Btl = Bth + (size_t)NN*DD;
  U16* Ath = (U16*)(out + (size_t)NN*DD);
  U16* Atl = Ath + (size_t)NN*DD;

  k_init<<<1, 64, 0, stream>>>(slots);
  k_sqsum<<<4096, 256, 0, stream>>>(A, B, sqA, sqB, slots);
  k_distm<<<dim3(64,64), 512, 0, stream>>>(A, B, q, sqA, sqB, slots);
  k_buildK<<<32768, 256, 0, stream>>>((U32*)q, slots);

  const uint4* Kp4 = (const uint4*)q;
  k_fused<1><<<1024, 256, 0, stream>>>(Kp4, v, u, partb);
  for (int it = 0; it < 200; ++it){
    k_vfin<<<256, 256, 0, stream>>>(partb, v);
    k_fused<0><<<1024, 256, 0, stream>>>(Kp4, v, u, partb);
  }

  k_At<<<dim3(12,128), 256, 0, stream>>>(A, v, Ath, Atl);
  k_outA<<<dim3(4,64), 512, 0, stream>>>(q, Ath, Atl, u, out);
  k_At<<<dim3(12,128), 256, 0, stream>>>(B, u, Bth, Btl);
  k_outBm<<<dim3(4,64), 512, 0, stream>>>(q, Bth, Btl, v, out + (size_t)NN*DD);
}